// Round 3
// baseline (168.115 us; speedup 1.0000x reference)
//
#include <hip/hip_runtime.h>

typedef unsigned short u16;
typedef __attribute__((ext_vector_type(4))) float f32x4;
typedef __attribute__((ext_vector_type(8))) short s16x8;

static constexpr int N_ = 4096;
static constexpr int D_ = 1024;

__device__ __forceinline__ u16 f2bf(float f) {
  unsigned u = __float_as_uint(f);
  u += 0x7FFFu + ((u >> 16) & 1u);   // RNE
  return (u16)(u >> 16);
}

__device__ __forceinline__ f32x4 zero4() {
  f32x4 z; z[0] = 0.f; z[1] = 0.f; z[2] = 0.f; z[3] = 0.f; return z;
}

// ---------------- K0: WpB bf16 conversion + Gacc zero + M = Pow @ Wsum ----------------
// blocks 0..15: WpB conversion + zero Gacc; blocks 16..143: (b,tile) -> M rows
__global__ __launch_bounds__(256) void k_prep(
    const float* __restrict__ Wpm, const float* __restrict__ piw,
    const float* __restrict__ pw, u16* __restrict__ WpB,
    u16* __restrict__ MB, float* __restrict__ Gacc) {
  int bid = blockIdx.x, tid = threadIdx.x;
  if (bid < 16) {
    size_t i0 = (size_t)bid * 4096;
    for (int idx = tid; idx < 4096; idx += 256)
      WpB[i0 + idx] = f2bf(piw[i0 + idx]);
    // zero Gacc: 32768 floats / 16 blocks = 2048 per block
    float* g = Gacc + (size_t)bid * 2048;
    for (int idx = tid; idx < 2048; idx += 256) g[idx] = 0.f;
    return;
  }
  __shared__ float Ws[64][65];
  int idx2 = bid - 16;
  int b = idx2 >> 4, t = idx2 & 15;
  for (int idx = tid; idx < 4096; idx += 256) {
    float s = 0.f;
#pragma unroll
    for (int k = 0; k < 8; ++k)
      s += Wpm[((size_t)(b * 8 + k)) * 4096 + idx];
    Ws[idx >> 6][idx & 63] = s;
  }
  __syncthreads();
  u16* mb = MB + ((size_t)b << 16);
  for (int oidx = tid; oidx < 4096; oidx += 256) {
    int r = oidx >> 6, c = oidx & 63;
    int drow = t * 64 + r;
    const float* prow = pw + (size_t)drow * 64;
    float acc = 0.f;
#pragma unroll 8
    for (int q = 0; q < 64; ++q) acc += prow[q] * Ws[q][c];
    mb[(size_t)drow * 64 + c] = f2bf(acc);
  }
}

// ---------------- K1: fused read/commit main pass ----------------
// grid = 8 batches * 64 row-tiles, 512 threads (8 waves), 64 rows/block.
// wave w: wm = w&3 -> 16-row tile, wk = w>>2 -> K-half / N-half.
__global__ __launch_bounds__(512, 4) void k_main(
    const float* __restrict__ H, const float* __restrict__ Sur,
    const float* __restrict__ pib, const float* __restrict__ pob,
    const float* __restrict__ sscale_p, const float* __restrict__ sbias_p,
    const u16* __restrict__ WpB, const u16* __restrict__ MB,
    float* __restrict__ Gacc, float* __restrict__ out) {
  __shared__ __align__(16) float preF[64][68];  // wk=1 partial pre (f32)
  __shared__ __align__(16) u16 preRP[64][72];   // pre (with bias), bf16, row-major
  __shared__ __align__(16) u16 wRPT[64][72];    // (sqrt(s)*pre) TRANSPOSED: [p][row]
  __shared__ float sqs[64];

  const int tid = threadIdx.x;
  const int lane = tid & 63;
  const int w = tid >> 6;
  const int wm = w & 3;
  const int wk = w >> 2;
  const int llo = lane & 15;
  const int lhi = lane >> 4;
  const int b = blockIdx.x >> 6;
  const int row0 = (blockIdx.x & 63) * 64;

  // ---- surprise row norms -> sqrt(sigmoid(scale*mag+bias)), 8 rows/wave ----
  {
    int r = w * 8 + (lane >> 3);
    const float* p = Sur + ((size_t)b * N_ + row0 + r) * D_ + (lane & 7) * 4;
    float a0 = 0.f, a1 = 0.f;
#pragma unroll
    for (int j = 0; j < 32; j += 2) {
      float4 v = *(const float4*)(p + j * 32);
      float4 v2 = *(const float4*)(p + j * 32 + 32);
      a0 += v.x * v.x + v.y * v.y + v.z * v.z + v.w * v.w;
      a1 += v2.x * v2.x + v2.y * v2.y + v2.z * v2.z + v2.w * v2.w;
    }
    float a = a0 + a1;
    a += __shfl_xor(a, 1, 64);
    a += __shfl_xor(a, 2, 64);
    a += __shfl_xor(a, 4, 64);
    if ((lane & 7) == 0) {
      float mag = sqrtf(a);
      float s = 1.f / (1.f + __expf(-(sscale_p[0] * mag + sbias_p[0])));
      sqs[r] = sqrtf(s);
    }
  }

  // ---- phase A: pre = H @ Wp^T, K split across wk, depth-4 H prefetch ----
  f32x4 accA[4];
#pragma unroll
  for (int t = 0; t < 4; ++t) accA[t] = zero4();
  {
    const float* hrow =
        H + ((size_t)b * N_ + row0 + wm * 16 + llo) * D_ + wk * 512 + lhi * 8;
    const u16* wp0 = WpB + (size_t)llo * 1024 + wk * 512 + lhi * 8;
    float4 A0[4], A1[4];
#pragma unroll
    for (int i = 0; i < 4; ++i) {
      A0[i] = *(const float4*)(hrow + i * 32);
      A1[i] = *(const float4*)(hrow + i * 32 + 4);
    }
#pragma unroll
    for (int kb = 0; kb < 512; kb += 128) {
#pragma unroll
      for (int jj = 0; jj < 4; ++jj) {
        const int k0 = kb + jj * 32;
        float4 a0 = A0[jj], a1 = A1[jj];
        if (k0 + 128 < 512) {   // compile-time after unroll
          A0[jj] = *(const float4*)(hrow + k0 + 128);
          A1[jj] = *(const float4*)(hrow + k0 + 132);
        }
        s16x8 af;
        af[0] = (short)f2bf(a0.x); af[1] = (short)f2bf(a0.y);
        af[2] = (short)f2bf(a0.z); af[3] = (short)f2bf(a0.w);
        af[4] = (short)f2bf(a1.x); af[5] = (short)f2bf(a1.y);
        af[6] = (short)f2bf(a1.z); af[7] = (short)f2bf(a1.w);
#pragma unroll
        for (int t = 0; t < 4; ++t) {
          s16x8 bf = *(const s16x8*)(wp0 + (size_t)t * 16384 + k0);
          accA[t] = __builtin_amdgcn_mfma_f32_16x16x32_bf16(af, bf, accA[t], 0, 0, 0);
        }
      }
    }
  }
  if (wk == 1) {
#pragma unroll
    for (int t = 0; t < 4; ++t)
#pragma unroll
      for (int r = 0; r < 4; ++r)
        preF[wm * 16 + lhi * 4 + r][t * 16 + llo] = accA[t][r];
  }
  __syncthreads();
  if (wk == 0) {
#pragma unroll
    for (int t = 0; t < 4; ++t) {
      float bias = pib[t * 16 + llo];
#pragma unroll
      for (int r = 0; r < 4; ++r) {
        int row = wm * 16 + lhi * 4 + r;
        float v = accA[t][r] + preF[row][t * 16 + llo] + bias;
        preRP[row][t * 16 + llo] = f2bf(v);
        wRPT[t * 16 + llo][row] = f2bf(v * sqs[row]);  // transposed store
      }
    }
  }
  __syncthreads();

  // ---- phase G: G += weighted^T @ weighted, K-rows split across wk ----
  {
    const int kbase = wk * 32;
    f32x4 accG[4];
#pragma unroll
    for (int t = 0; t < 4; ++t) accG[t] = zero4();
    s16x8 ag = *(const s16x8*)&wRPT[wm * 16 + llo][kbase + lhi * 8];
#pragma unroll
    for (int t = 0; t < 4; ++t) {
      s16x8 bg = *(const s16x8*)&wRPT[t * 16 + llo][kbase + lhi * 8];
      accG[t] = __builtin_amdgcn_mfma_f32_16x16x32_bf16(ag, bg, accG[t], 0, 0, 0);
    }
    float* gb = Gacc + (size_t)b * 4096;
#pragma unroll
    for (int t = 0; t < 4; ++t)
#pragma unroll
      for (int r = 0; r < 4; ++r)
        atomicAdd(gb + (wm * 16 + lhi * 4 + r) * 64 + t * 16 + llo, accG[t][r]);
  }

  // ---- phase D: pm_read = pre @ M^T + bias, N-cols split across wk ----
  {
    s16x8 ad0 = *(const s16x8*)&preRP[wm * 16 + llo][lhi * 8];
    s16x8 ad1 = *(const s16x8*)&preRP[wm * 16 + llo][32 + lhi * 8];
    const u16* mb = MB + ((size_t)b << 16);
    const int nb = wk * 512;
    const u16* mrow0 = mb + (size_t)(nb + llo) * 64 + lhi * 8;
    float* orow = out + ((size_t)b * N_ + row0 + wm * 16) * D_;
    s16x8 B0[2], B1[2];
    B0[0] = *(const s16x8*)(mrow0);
    B1[0] = *(const s16x8*)(mrow0 + 32);
    B0[1] = *(const s16x8*)(mrow0 + 1024);
    B1[1] = *(const s16x8*)(mrow0 + 1024 + 32);
#pragma unroll 2
    for (int i = 0; i < 32; ++i) {
      const int j = i & 1;             // static after unroll 2
      s16x8 b0 = B0[j], b1 = B1[j];
      int ipf = (i + 2 < 32) ? (i + 2) : i;  // clamped prefetch (re-load ok)
      B0[j] = *(const s16x8*)(mrow0 + (size_t)ipf * 1024);
      B1[j] = *(const s16x8*)(mrow0 + (size_t)ipf * 1024 + 32);
      f32x4 acc = zero4();
      acc = __builtin_amdgcn_mfma_f32_16x16x32_bf16(ad0, b0, acc, 0, 0, 0);
      acc = __builtin_amdgcn_mfma_f32_16x16x32_bf16(ad1, b1, acc, 0, 0, 0);
      const int n0 = nb + i * 16;
      float bias = pob[n0 + llo];
#pragma unroll
      for (int r = 0; r < 4; ++r)
        orow[(size_t)(lhi * 4 + r) * D_ + n0 + llo] = acc[r] + bias;
    }
  }
}

// ---------------- K2: W_new = W_pm @ (decay*I + beta*G/N), frob clip ----------------
__global__ __launch_bounds__(256) void k_wnew(
    const float* __restrict__ Wpm, const float* __restrict__ Gacc,
    const float* __restrict__ rbeta, const float* __restrict__ rdecay,
    float* __restrict__ outW) {
  __shared__ float Wk[64][66];
  __shared__ float Gl[64][66];
  __shared__ float red[4];
  int bk = blockIdx.x;
  int b = bk >> 3, k = bk & 7;
  int tid = threadIdx.x;
  const float* wsrc = Wpm + (size_t)bk * 4096;
  const float* gsrc = Gacc + (size_t)b * 4096;
  for (int idx = tid; idx < 4096; idx += 256) {
    Wk[idx >> 6][idx & 63] = wsrc[idx];
    Gl[idx >> 6][idx & 63] = gsrc[idx];
  }
  __syncthreads();
  float beta = log1pf(__expf(rbeta[k]));
  float decay = 1.f / (1.f + __expf(-rdecay[k]));
  float bn = beta * (1.f / 4096.f);
  int q = tid & 63;
  int rbase = tid >> 6;
  float vals[16];
  float ss = 0.f;
#pragma unroll
  for (int i = 0; i < 16; ++i) {
    int row = i * 4 + rbase;
    float acc = 0.f;
#pragma unroll 8
    for (int j = 0; j < 64; ++j) acc += Wk[row][j] * Gl[j][q];
    float v = decay * Wk[row][q] + bn * acc;
    vals[i] = v;
    ss += v * v;
  }
#pragma unroll
  for (int m = 1; m < 64; m <<= 1) ss += __shfl_xor(ss, m, 64);
  if ((tid & 63) == 0) red[tid >> 6] = ss;
  __syncthreads();
  float frob = sqrtf(red[0] + red[1] + red[2] + red[3]);
  float scale = fminf(16.f / fmaxf(frob, 1e-8f), 1.f);
  float* dst = outW + (size_t)bk * 4096;
#pragma unroll
  for (int i = 0; i < 16; ++i) dst[i * 256 + tid] = vals[i] * scale;
}

extern "C" void kernel_launch(void* const* d_in, const int* in_sizes, int n_in,
                              void* d_out, int out_size, void* d_ws, size_t ws_size,
                              hipStream_t stream) {
  const float* H      = (const float*)d_in[0];
  const float* Sur    = (const float*)d_in[1];
  const float* Wpm    = (const float*)d_in[2];
  const float* piw    = (const float*)d_in[3];
  const float* pib    = (const float*)d_in[4];
  const float* pw     = (const float*)d_in[5];
  const float* pob    = (const float*)d_in[6];
  const float* rbeta  = (const float*)d_in[7];
  const float* rdecay = (const float*)d_in[8];
  const float* sscale = (const float*)d_in[9];
  const float* sbias  = (const float*)d_in[10];
  float* out = (float*)d_out;

  char* ws = (char*)d_ws;
  float* Gacc = (float*)(ws);                 // [8][64][64] f32    = 131072 B
  u16* WpB    = (u16*)(ws + 131072);          // [64][1024] bf16    = 131072 B
  u16* MB     = (u16*)(ws + 262144);          // [8][1024][64] bf16 = 1 MB

  k_prep<<<144, 256, 0, stream>>>(Wpm, piw, pw, WpB, MB, Gacc);
  k_main<<<512, 512, 0, stream>>>(H, Sur, pib, pob, sscale, sbias,
                                  WpB, MB, Gacc, out);
  k_wnew<<<64, 256, 0, stream>>>(Wpm, Gacc, rbeta, rdecay,
                                 out + (size_t)8 * 4096 * 1024);
}

// Round 4
// 162.298 us; speedup vs baseline: 1.0358x; 1.0358x over previous
//
#include <hip/hip_runtime.h>

typedef unsigned short u16;
typedef unsigned int u32;
typedef __attribute__((ext_vector_type(4))) float f32x4;
typedef __attribute__((ext_vector_type(8))) short s16x8;

static constexpr int N_ = 4096;
static constexpr int D_ = 1024;

#define WAITV(N) asm volatile("s_waitcnt vmcnt(" #N ")" ::: "memory")
#define MEMCLOB() asm volatile("" ::: "memory")

__device__ __forceinline__ u16 f2bf(float f) {
  unsigned u = __float_as_uint(f);
  u += 0x7FFFu + ((u >> 16) & 1u);  // RNE
  return (u16)(u >> 16);
}

__device__ __forceinline__ f32x4 zero4() {
  f32x4 z; z[0] = 0.f; z[1] = 0.f; z[2] = 0.f; z[3] = 0.f; return z;
}

__device__ __forceinline__ void gload16(const void* g, void* lds) {
  __builtin_amdgcn_global_load_lds(
      (const __attribute__((address_space(1))) u32*)g,
      (__attribute__((address_space(3))) u32*)lds, 16, 0, 0);
}

// ---------------- K0: prep (WpB, MB) + surprise norms ----------------
// blocks 0..15: WpB bf16; 16..143: M = Pow @ Wsum; 144..2191: row norms.
__global__ __launch_bounds__(256) void k_aux(
    const float* __restrict__ Wpm, const float* __restrict__ piw,
    const float* __restrict__ pw, const float* __restrict__ Sur,
    const float* __restrict__ sscale_p, const float* __restrict__ sbias_p,
    u16* __restrict__ WpB, u16* __restrict__ MB, float* __restrict__ sqs_ws) {
  __shared__ float Ws[64][65];
  int bid = blockIdx.x, tid = threadIdx.x;
  if (bid < 16) {
    size_t i0 = (size_t)bid * 4096;
    for (int idx = tid; idx < 4096; idx += 256)
      WpB[i0 + idx] = f2bf(piw[i0 + idx]);
    return;
  }
  if (bid < 144) {
    int idx2 = bid - 16;
    int b = idx2 >> 4, t = idx2 & 15;
    for (int idx = tid; idx < 4096; idx += 256) {
      float s = 0.f;
#pragma unroll
      for (int k = 0; k < 8; ++k)
        s += Wpm[((size_t)(b * 8 + k)) * 4096 + idx];
      Ws[idx >> 6][idx & 63] = s;
    }
    __syncthreads();
    u16* mb = MB + ((size_t)b << 16);
    for (int oidx = tid; oidx < 4096; oidx += 256) {
      int r = oidx >> 6, c = oidx & 63;
      int drow = t * 64 + r;
      const float* prow = pw + (size_t)drow * 64;
      float acc = 0.f;
#pragma unroll 8
      for (int q = 0; q < 64; ++q) acc += prow[q] * Ws[q][c];
      mb[(size_t)drow * 64 + c] = f2bf(acc);
    }
    return;
  }
  // ---- norms: 4 waves, 4 rows each ----
  int w = tid >> 6, lane = tid & 63;
  int fr = (bid - 144) * 16 + w * 4;
  const float4* r0 = (const float4*)(Sur + (size_t)fr * 1024) + lane;
  float s0 = 0.f, s1 = 0.f, s2 = 0.f, s3 = 0.f;
#pragma unroll
  for (int c = 0; c < 4; ++c) {
    float4 v0 = r0[c * 64];
    float4 v1 = r0[256 + c * 64];
    float4 v2 = r0[512 + c * 64];
    float4 v3 = r0[768 + c * 64];
    s0 += v0.x * v0.x + v0.y * v0.y + v0.z * v0.z + v0.w * v0.w;
    s1 += v1.x * v1.x + v1.y * v1.y + v1.z * v1.z + v1.w * v1.w;
    s2 += v2.x * v2.x + v2.y * v2.y + v2.z * v2.z + v2.w * v2.w;
    s3 += v3.x * v3.x + v3.y * v3.y + v3.z * v3.z + v3.w * v3.w;
  }
#pragma unroll
  for (int m = 1; m < 64; m <<= 1) {
    s0 += __shfl_xor(s0, m, 64);
    s1 += __shfl_xor(s1, m, 64);
    s2 += __shfl_xor(s2, m, 64);
    s3 += __shfl_xor(s3, m, 64);
  }
  float res = s0;
  if (lane == 1) res = s1;
  if (lane == 2) res = s2;
  if (lane == 3) res = s3;
  if (lane < 4) {
    float mag = sqrtf(res);
    float s = 1.f / (1.f + __expf(-(sscale_p[0] * mag + sbias_p[0])));
    sqs_ws[fr + lane] = sqrtf(s);
  }
}

// ---------------- K1: fused read/commit main pass ----------------
// 512 blocks (8 b x 64 tiles), 512 threads (8 waves). wave: wm=w&3 (16 rows),
// wk=w>>2 (K-half in A / k-rows in G / N-half in D).
__global__ __launch_bounds__(512, 4) void k_main(
    const float* __restrict__ H, const float* __restrict__ pib,
    const float* __restrict__ pob, const u16* __restrict__ WpB,
    const u16* __restrict__ MB, const float* __restrict__ sqs_ws,
    float* __restrict__ Gpart, float* __restrict__ out) {
  __shared__ __align__(16) char arena[32768];  // Hs/MBs[2 buf][2 slab][8192] | preF
  __shared__ __align__(16) u16 preRP[64][72];
  __shared__ __align__(16) u16 wRPT[64][72];
  __shared__ float pobL[1024];

  const int tid = threadIdx.x;
  const int lane = tid & 63;
  const int w = tid >> 6;
  const int wm = w & 3;
  const int wk = w >> 2;
  const int llo = lane & 15;
  const int lhi = lane >> 4;
  const int b = blockIdx.x >> 6;
  const int row0 = (blockIdx.x & 63) * 64;

  // small operands into regs early (latency fully hidden)
  float bias_t[4];
#pragma unroll
  for (int t = 0; t < 4; ++t) bias_t[t] = pib[t * 16 + llo];
  float sqs_r[4];
#pragma unroll
  for (int r = 0; r < 4; ++r)
    sqs_r[r] = sqs_ws[b * 4096 + row0 + wm * 16 + lhi * 4 + r];

  // staging lane params (shared by phase A and D)
  const int srow = 8 * w + (lane >> 3);          // row 0..63 staged by this lane
  const int sc16 = (lane & 7) ^ (srow & 7);      // pre-swizzled logical 16B chunk

  // ---------------- phase A: pre = H @ Wp^T ----------------
  f32x4 accA[4];
#pragma unroll
  for (int t = 0; t < 4; ++t) accA[t] = zero4();

  const float* hsrc = H + ((size_t)b * N_ + row0 + srow) * D_ + sc16 * 4;
  const u16* wpb = WpB + (size_t)wk * 512 + lhi * 8;

  s16x8 B0[4], B1[4];
  auto LOADB = [&](int kc, s16x8* Bs) {
#pragma unroll
    for (int t = 0; t < 4; ++t)
      Bs[t] = *(const s16x8*)(wpb + (size_t)(t * 16 + llo) * 1024 + kc * 32);
  };
  auto STAGEH = [&](int kc, int buf) {
    gload16(hsrc + kc * 32, arena + buf * 16384 + w * 1024);
    gload16(hsrc + 512 + kc * 32, arena + buf * 16384 + 8192 + w * 1024);
  };
  const int arow = wm * 16 + llo;
  const int r7a = arow & 7;
  auto COMPA = [&](int buf, const s16x8* Bs) {
    const char* abase = arena + buf * 16384 + wk * 8192 + arow * 128;
    f32x4 alo = *(const f32x4*)(abase + (((lhi * 2) ^ r7a) * 16));
    f32x4 ahi = *(const f32x4*)(abase + (((lhi * 2 + 1) ^ r7a) * 16));
    s16x8 af;
    af[0] = (short)f2bf(alo[0]); af[1] = (short)f2bf(alo[1]);
    af[2] = (short)f2bf(alo[2]); af[3] = (short)f2bf(alo[3]);
    af[4] = (short)f2bf(ahi[0]); af[5] = (short)f2bf(ahi[1]);
    af[6] = (short)f2bf(ahi[2]); af[7] = (short)f2bf(ahi[3]);
#pragma unroll
    for (int t = 0; t < 4; ++t)
      accA[t] = __builtin_amdgcn_mfma_f32_16x16x32_bf16(af, Bs[t], accA[t], 0, 0, 0);
  };

  LOADB(0, B0); STAGEH(0, 0);
  MEMCLOB();
  LOADB(1, B1); STAGEH(1, 1);
  MEMCLOB();

  for (int kc = 0; kc < 16; kc += 2) {
    WAITV(6);
    __builtin_amdgcn_s_barrier();
    COMPA(0, B0);
    MEMCLOB();
    __builtin_amdgcn_s_barrier();
    if (kc + 2 < 16) { LOADB(kc + 2, B0); STAGEH(kc + 2, 0); }
    MEMCLOB();
    if (kc + 1 == 15) { WAITV(0); } else { WAITV(6); }
    __builtin_amdgcn_s_barrier();
    COMPA(1, B1);
    MEMCLOB();
    __builtin_amdgcn_s_barrier();
    if (kc + 3 < 16) { LOADB(kc + 3, B1); STAGEH(kc + 3, 1); }
    MEMCLOB();
  }

  // ---------------- epilogue: combine K-halves, write pre/weighted ----------------
  __syncthreads();
  float (*preF)[65] = (float(*)[65])arena;
  if (wk == 1) {
#pragma unroll
    for (int t = 0; t < 4; ++t)
#pragma unroll
      for (int r = 0; r < 4; ++r)
        preF[wm * 16 + lhi * 4 + r][t * 16 + llo] = accA[t][r];
  }
  __syncthreads();
  if (wk == 0) {
#pragma unroll
    for (int t = 0; t < 4; ++t)
#pragma unroll
      for (int r = 0; r < 4; ++r) {
        int row = wm * 16 + lhi * 4 + r;
        float v = accA[t][r] + preF[row][t * 16 + llo] + bias_t[t];
        preRP[row][t * 16 + llo] = f2bf(v);
        wRPT[t * 16 + llo][row] = f2bf(v * sqs_r[r]);
      }
  }
  __syncthreads();

  // ---------------- phase G: per-block partial G = weighted^T @ weighted ----------------
  {
    f32x4 accG[4];
#pragma unroll
    for (int t = 0; t < 4; ++t) accG[t] = zero4();
    s16x8 ag = *(const s16x8*)&wRPT[wm * 16 + llo][wk * 32 + lhi * 8];
#pragma unroll
    for (int t = 0; t < 4; ++t) {
      s16x8 bg = *(const s16x8*)&wRPT[t * 16 + llo][wk * 32 + lhi * 8];
      accG[t] = __builtin_amdgcn_mfma_f32_16x16x32_bf16(ag, bg, accG[t], 0, 0, 0);
    }
    float* gout = Gpart + ((size_t)blockIdx.x * 2 + wk) * 4096;
#pragma unroll
    for (int t = 0; t < 4; ++t)
#pragma unroll
      for (int r = 0; r < 4; ++r)
        gout[(wm * 16 + lhi * 4 + r) * 64 + t * 16 + llo] = accG[t][r];
  }

  // pob into LDS (latency absorbed by the next syncthreads drain)
  pobL[tid] = pob[tid];
  pobL[tid + 512] = pob[tid + 512];
  __syncthreads();  // drains Gpart stores + pob loads; arena now free for MBs

  // ---------------- phase D: pm_read = pre @ M^T + bias ----------------
  const u16* mbb = MB + ((size_t)b << 16);
  const u16* msrc0 = mbb + (size_t)srow * 64 + sc16 * 8;
  auto STAGED = [&](int c, int buf) {
    gload16(msrc0 + (size_t)c * 64 * 64, arena + buf * 16384 + w * 1024);
    gload16(msrc0 + (size_t)(512 + c * 64) * 64, arena + buf * 16384 + 8192 + w * 1024);
  };
  s16x8 ad0 = *(const s16x8*)&preRP[wm * 16 + llo][lhi * 8];
  s16x8 ad1 = *(const s16x8*)&preRP[wm * 16 + llo][32 + lhi * 8];
  float* orow = out + ((size_t)b * N_ + row0 + wm * 16) * D_;

  STAGED(0, 0);
  MEMCLOB();
  STAGED(1, 1);
  MEMCLOB();
  for (int c = 0; c < 8; ++c) {
    if (c == 0) { WAITV(2); }
    else if (c == 7) { WAITV(16); }
    else { WAITV(18); }
    __builtin_amdgcn_s_barrier();
    {
      const char* dbase = arena + (c & 1) * 16384 + wk * 8192;
#pragma unroll
      for (int i = 0; i < 4; ++i) {
        int row = i * 16 + llo;
        int r7 = row & 7;
        const char* base = dbase + row * 128;
        s16x8 b0 = *(const s16x8*)(base + ((lhi ^ r7) * 16));
        s16x8 b1 = *(const s16x8*)(base + (((4 + lhi) ^ r7) * 16));
        f32x4 acc = zero4();
        acc = __builtin_amdgcn_mfma_f32_16x16x32_bf16(ad0, b0, acc, 0, 0, 0);
        acc = __builtin_amdgcn_mfma_f32_16x16x32_bf16(ad1, b1, acc, 0, 0, 0);
        int n0 = wk * 512 + c * 64 + i * 16;
        float bias = pobL[n0 + llo];
#pragma unroll
        for (int r = 0; r < 4; ++r)
          orow[(size_t)(lhi * 4 + r) * D_ + n0 + llo] = acc[r] + bias;
      }
    }
    MEMCLOB();
    __builtin_amdgcn_s_barrier();
    if (c + 2 < 8) STAGED(c + 2, c & 1);
    MEMCLOB();
  }
}

// ---------------- K2: G-reduce + W_new = W_pm@(decay*I + beta*G/N), frob clip ----------------
__global__ __launch_bounds__(256) void k_wnew(
    const float* __restrict__ Wpm, const float* __restrict__ Gpart,
    const float* __restrict__ rbeta, const float* __restrict__ rdecay,
    float* __restrict__ outW) {
  __shared__ float Wk[64][68];
  __shared__ float Gl[64][68];
  __shared__ float red[4];
  int bk = blockIdx.x;
  int b = bk >> 3, k = bk & 7;
  int tid = threadIdx.x;
  // reduce 128 per-block partials for this b
  f32x4 a0 = zero4(), a1 = zero4(), a2 = zero4(), a3 = zero4();
  const float* gp = Gpart + (size_t)b * 128 * 4096 + tid * 16;
#pragma unroll 2
  for (int sl = 0; sl < 128; ++sl) {
    const f32x4* p = (const f32x4*)(gp + (size_t)sl * 4096);
    a0 += p[0]; a1 += p[1]; a2 += p[2]; a3 += p[3];
  }
  {
    float* gl = &Gl[tid >> 2][(tid & 3) * 16];
#pragma unroll
    for (int j = 0; j < 4; ++j) {
      gl[j] = a0[j]; gl[4 + j] = a1[j]; gl[8 + j] = a2[j]; gl[12 + j] = a3[j];
    }
  }
  const float* wsrc = Wpm + (size_t)bk * 4096;
  for (int idx = tid; idx < 4096; idx += 256)
    Wk[idx >> 6][idx & 63] = wsrc[idx];
  __syncthreads();
  float beta = log1pf(__expf(rbeta[k]));
  float decay = 1.f / (1.f + __expf(-rdecay[k]));
  float bn = beta * (1.f / 4096.f);  // G partials are unnormalized
  int q = tid & 63;
  int rbase = tid >> 6;
  float vals[16];
  float ss = 0.f;
#pragma unroll
  for (int i = 0; i < 16; ++i) {
    int row = i * 4 + rbase;
    float acc = 0.f;
#pragma unroll 8
    for (int j = 0; j < 64; ++j) acc += Wk[row][j] * Gl[j][q];
    float v = decay * Wk[row][q] + bn * acc;
    vals[i] = v;
    ss += v * v;
  }
#pragma unroll
  for (int m = 1; m < 64; m <<= 1) ss += __shfl_xor(ss, m, 64);
  if ((tid & 63) == 0) red[tid >> 6] = ss;
  __syncthreads();
  float frob = sqrtf(red[0] + red[1] + red[2] + red[3]);
  float scale = fminf(16.f / fmaxf(frob, 1e-8f), 1.f);
  float* dst = outW + (size_t)bk * 4096;
#pragma unroll
  for (int i = 0; i < 16; ++i) dst[i * 256 + tid] = vals[i] * scale;
}

extern "C" void kernel_launch(void* const* d_in, const int* in_sizes, int n_in,
                              void* d_out, int out_size, void* d_ws, size_t ws_size,
                              hipStream_t stream) {
  const float* H      = (const float*)d_in[0];
  const float* Sur    = (const float*)d_in[1];
  const float* Wpm    = (const float*)d_in[2];
  const float* piw    = (const float*)d_in[3];
  const float* pib    = (const float*)d_in[4];
  const float* pw     = (const float*)d_in[5];
  const float* pob    = (const float*)d_in[6];
  const float* rbeta  = (const float*)d_in[7];
  const float* rdecay = (const float*)d_in[8];
  const float* sscale = (const float*)d_in[9];
  const float* sbias  = (const float*)d_in[10];
  float* out = (float*)d_out;

  char* ws = (char*)d_ws;
  u16* WpB      = (u16*)(ws);                   // [64][1024] bf16      = 131072 B
  u16* MB       = (u16*)(ws + 131072);          // [8][1024][64] bf16   = 1 MB
  float* sqs_ws = (float*)(ws + 1179648);       // [8][4096] f32        = 131072 B
  float* Gpart  = (float*)(ws + 1310720);       // [1024][64][64] f32   = 16 MB

  k_aux<<<2192, 256, 0, stream>>>(Wpm, piw, pw, Sur, sscale, sbias,
                                  WpB, MB, sqs_ws);
  k_main<<<512, 512, 0, stream>>>(H, pib, pob, WpB, MB, sqs_ws, Gpart, out);
  k_wnew<<<64, 256, 0, stream>>>(Wpm, Gpart, rbeta, rdecay,
                                 out + (size_t)8 * 4096 * 1024);
}